// Round 1
// baseline (492.709 us; speedup 1.0000x reference)
//
#include <hip/hip_runtime.h>

typedef _Float16 f16;
typedef f16  f16x8 __attribute__((ext_vector_type(8)));
typedef f16  f16x4v __attribute__((ext_vector_type(4)));
typedef float f32x4 __attribute__((ext_vector_type(4)));

#define SEQ 2048
#define EMB 1024
#define NH  16
#define HD  64
#define SCAL 0.125f

// ---------------- fp32 -> fp16 convert ----------------
__global__ void cvt_f32_f16(const float* __restrict__ src, f16* __restrict__ dst, int n) {
    int i = (blockIdx.x * blockDim.x + threadIdx.x) * 4;
    if (i >= n) return;
    float4 v = *(const float4*)(src + i);
    f16x4v o;
    o[0] = (f16)v.x; o[1] = (f16)v.y; o[2] = (f16)v.z; o[3] = (f16)v.w;
    *(f16x4v*)(dst + i) = o;
}

// ---------------- GEMM: C = A @ B^T (+bias), fp16 in, epilogues ----------------
// A [M,1024] row-major fp16, B [N,1024] row-major fp16 (so C = A·B^T).
// MODE 0: QKV projection epilogue (N=3072): q scaled+fp16->[B,H,S,D], k fp16->[B,H,S,D],
//         v fp16 -> transposed [B,H,D,S].
// MODE 1: out projection: fp32 store to fo[m*1024+n] + bias b0.
template<int MODE>
__global__ __launch_bounds__(256) void gemm16(
    const f16* __restrict__ A, const f16* __restrict__ B,
    const float* __restrict__ b0, const float* __restrict__ b1, const float* __restrict__ b2,
    f16* __restrict__ qo, f16* __restrict__ ko, f16* __restrict__ vo,
    float* __restrict__ fo)
{
    __shared__ f16 As[128 * 40];   // +8 pad per row: kills b128 read conflicts
    __shared__ f16 Bs[128 * 40];
    const int tid  = threadIdx.x;
    const int wave = tid >> 6, lane = tid & 63;
    const int g = lane >> 4, li = lane & 15;
    const int wr = wave >> 1, wc = wave & 1;
    const int bm = blockIdx.x * 128, bn = blockIdx.y * 128;

    const f32x4 vzero = {0.f, 0.f, 0.f, 0.f};
    f32x4 acc[4][4];
#pragma unroll
    for (int i = 0; i < 4; ++i)
#pragma unroll
        for (int j = 0; j < 4; ++j) acc[i][j] = vzero;

#pragma unroll 1
    for (int kk = 0; kk < 1024; kk += 32) {
#pragma unroll
        for (int i = 0; i < 2; ++i) {
            int c   = tid + i * 256;
            int row = c >> 2, seg = (c & 3) * 8;
            f16x8 va = *(const f16x8*)(A + (size_t)(bm + row) * 1024 + kk + seg);
            f16x8 vb = *(const f16x8*)(B + (size_t)(bn + row) * 1024 + kk + seg);
            *(f16x8*)(&As[row * 40 + seg]) = va;
            *(f16x8*)(&Bs[row * 40 + seg]) = vb;
        }
        __syncthreads();
        f16x8 af[4];
#pragma unroll
        for (int mi = 0; mi < 4; ++mi)
            af[mi] = *(const f16x8*)(&As[(wr * 64 + mi * 16 + li) * 40 + g * 8]);
#pragma unroll
        for (int ni = 0; ni < 4; ++ni) {
            f16x8 bf = *(const f16x8*)(&Bs[(wc * 64 + ni * 16 + li) * 40 + g * 8]);
#pragma unroll
            for (int mi = 0; mi < 4; ++mi)
                acc[mi][ni] = __builtin_amdgcn_mfma_f32_16x16x32_f16(af[mi], bf, acc[mi][ni], 0, 0, 0);
        }
        __syncthreads();
    }

    // Epilogue. C/D frag: col = lane&15, row = (lane>>4)*4 + reg.
#pragma unroll
    for (int mi = 0; mi < 4; ++mi)
#pragma unroll
        for (int ni = 0; ni < 4; ++ni) {
            int nc = bn + wc * 64 + ni * 16 + li;
#pragma unroll
            for (int r = 0; r < 4; ++r) {
                int   mr = bm + wr * 64 + mi * 16 + g * 4 + r;
                float v  = acc[mi][ni][r];
                if (MODE == 0) {
                    int which = nc >> 10, rr = nc & 1023;
                    int h = rr >> 6, d = rr & 63;
                    int b = mr >> 11, s = mr & 2047;
                    size_t qkidx = ((size_t)((b * NH + h) * SEQ + s)) * HD + d;
                    if (which == 0)      qo[qkidx] = (f16)((v + b0[rr]) * SCAL);
                    else if (which == 1) ko[qkidx] = (f16)(v + b1[rr]);
                    else                 vo[((size_t)((b * NH + h) * HD + d)) * SEQ + s] = (f16)(v + b2[rr]);
                } else {
                    fo[(size_t)mr * 1024 + nc] = v + b0[nc];
                }
            }
        }
}

// ---------------- Attention ----------------
// Grid: 256 blocks = (b in 0..1) x (128 q-tiles of 16 rows). Block: 1024 thr = 16 waves.
// Wave w owns k-slice [w*128, w*128+128). Heads looped inside the block so the
// head-mean accumulates in registers (no atomics, single coalesced write).
__global__ __launch_bounds__(1024) void attn16(
    const f16* __restrict__ Q, const f16* __restrict__ K, const f16* __restrict__ Vt,
    f16* __restrict__ ctx, float* __restrict__ meanw)
{
    __shared__ __align__(16) char pbuf[16][4112];  // per-wave region: P (16x128 f16) / O (16x64 f32)
    __shared__ float stats[16][16];                // [wave][q-row]
    __shared__ float fin[2][16];                   // row max / row sum
    const int tid = threadIdx.x;
    const int w = tid >> 6, lane = tid & 63;
    const int g = lane >> 4, li = lane & 15;
    const int b = blockIdx.x >> 7, qt = blockIdx.x & 127;
    const int q0 = qt * 16;
    const int kbase = w * 128;
    char* myp = pbuf[w];

    float meanacc[8][4];
#pragma unroll
    for (int c = 0; c < 8; ++c)
#pragma unroll
        for (int r = 0; r < 4; ++r) meanacc[c][r] = 0.f;

    const f32x4 vzero = {0.f, 0.f, 0.f, 0.f};

#pragma unroll 1
    for (int h = 0; h < NH; ++h) {
        const f16* __restrict__ Qh = Q  + ((size_t)((b * NH + h) * SEQ + q0)) * HD;
        const f16* __restrict__ Kh = K  + ((size_t)(b * NH + h)) * SEQ * HD;
        const f16* __restrict__ Vh = Vt + ((size_t)(b * NH + h)) * HD * SEQ;

        // Q A-frags: lane -> row=li, d = g*8 (+32)
        f16x8 qf0 = *(const f16x8*)(Qh + li * HD + g * 8);
        f16x8 qf1 = *(const f16x8*)(Qh + li * HD + 32 + g * 8);

        // S = Q K^T over this wave's 128 k-cols: 8 col-tiles
        f32x4 sc[8];
#pragma unroll
        for (int c = 0; c < 8; ++c) {
            sc[c] = vzero;
            const f16* kp = Kh + (size_t)(kbase + c * 16 + li) * HD + g * 8;
            f16x8 k0 = *(const f16x8*)(kp);
            f16x8 k1 = *(const f16x8*)(kp + 32);
            sc[c] = __builtin_amdgcn_mfma_f32_16x16x32_f16(qf0, k0, sc[c], 0, 0, 0);
            sc[c] = __builtin_amdgcn_mfma_f32_16x16x32_f16(qf1, k1, sc[c], 0, 0, 0);
        }

        // row max over this slice (rows g*4+r live across the 16 lanes of the group)
        float mx[4];
#pragma unroll
        for (int r = 0; r < 4; ++r) {
            float m = sc[0][r];
#pragma unroll
            for (int c = 1; c < 8; ++c) m = fmaxf(m, sc[c][r]);
#pragma unroll
            for (int d = 1; d < 16; d <<= 1) m = fmaxf(m, __shfl_xor(m, d));
            mx[r] = m;
        }
        if (li == 0) {
#pragma unroll
            for (int r = 0; r < 4; ++r) stats[w][g * 4 + r] = mx[r];
        }
        __syncthreads();
        if (tid < 16) {
            float m = stats[0][tid];
#pragma unroll
            for (int ww = 1; ww < 16; ++ww) m = fmaxf(m, stats[ww][tid]);
            fin[0][tid] = m;
        }
        __syncthreads();

        // exp + row sum
        float sm[4];
#pragma unroll
        for (int r = 0; r < 4; ++r) {
            float rm = fin[0][g * 4 + r];
            float s = 0.f;
#pragma unroll
            for (int c = 0; c < 8; ++c) {
                float e = __expf(sc[c][r] - rm);
                sc[c][r] = e;
                s += e;
            }
#pragma unroll
            for (int d = 1; d < 16; d <<= 1) s += __shfl_xor(s, d);
            sm[r] = s;
        }
        if (li == 0) {
#pragma unroll
            for (int r = 0; r < 4; ++r) stats[w][g * 4 + r] = sm[r];
        }
        __syncthreads();
        if (tid < 16) {
            float s = 0.f;
#pragma unroll
            for (int ww = 0; ww < 16; ++ww) s += stats[ww][tid];
            fin[1][tid] = s;
        }
        __syncthreads();

        // P = e / rowsum; accumulate mean; stage P into own LDS region (XOR-swizzled)
#pragma unroll
        for (int r = 0; r < 4; ++r) {
            float inv = 1.f / fin[1][g * 4 + r];
            int row = g * 4 + r;
#pragma unroll
            for (int c = 0; c < 8; ++c) {
                float p = sc[c][r] * inv;
                meanacc[c][r] += p;
                int off = row * 256 + (((c * 16 + li) * 2) ^ ((row & 7) << 4));
                *(f16*)(myp + off) = (f16)p;
            }
        }
        __syncthreads();

        // PV: O[16q x 64d] partial over this wave's k-slice
        f32x4 o[4];
#pragma unroll
        for (int dt = 0; dt < 4; ++dt) o[dt] = vzero;
#pragma unroll
        for (int ks = 0; ks < 4; ++ks) {
            f16x8 pf = *(const f16x8*)(myp + li * 256 + (((ks * 64 + g * 16)) ^ ((li & 7) << 4)));
#pragma unroll
            for (int dt = 0; dt < 4; ++dt) {
                f16x8 vf = *(const f16x8*)(Vh + (size_t)(dt * 16 + li) * SEQ + kbase + ks * 32 + g * 8);
                o[dt] = __builtin_amdgcn_mfma_f32_16x16x32_f16(pf, vf, o[dt], 0, 0, 0);
            }
        }
        // own-region overwrite: same-wave LDS ordering makes this safe
        float* myo = (float*)myp;
#pragma unroll
        for (int dt = 0; dt < 4; ++dt)
#pragma unroll
            for (int r = 0; r < 4; ++r)
                myo[(g * 4 + r) * 64 + dt * 16 + li] = o[dt][r];
        __syncthreads();
        {   // cross-wave O reduce + ctx write
            int qr = tid >> 6, d = tid & 63;
            float s = 0.f;
#pragma unroll
            for (int ww = 0; ww < 16; ++ww) s += ((const float*)pbuf[ww])[qr * 64 + d];
            ctx[((size_t)(b * SEQ + q0 + qr)) * EMB + h * HD + d] = (f16)s;
        }
        __syncthreads();
    }

    // mean over heads -> d_out tail [2,2048,2048]
#pragma unroll
    for (int r = 0; r < 4; ++r) {
        int qrow = q0 + g * 4 + r;
#pragma unroll
        for (int c = 0; c < 8; ++c)
            meanw[(size_t)b * SEQ * SEQ + (size_t)qrow * SEQ + kbase + c * 16 + li]
                = meanacc[c][r] * (1.f / 16.f);
    }
}

// ---------------- launch ----------------
extern "C" void kernel_launch(void* const* d_in, const int* in_sizes, int n_in,
                              void* d_out, int out_size, void* d_ws, size_t ws_size,
                              hipStream_t stream) {
    (void)in_sizes; (void)n_in; (void)out_size; (void)ws_size;
    const float* query = (const float*)d_in[0];
    const float* Wq = (const float*)d_in[1];
    const float* bq = (const float*)d_in[2];
    const float* Wk = (const float*)d_in[3];
    const float* bk = (const float*)d_in[4];
    const float* Wv = (const float*)d_in[5];
    const float* bv = (const float*)d_in[6];
    const float* Wo = (const float*)d_in[7];
    const float* bo = (const float*)d_in[8];
    float* out   = (float*)d_out;
    float* meanw = out + (size_t)2 * SEQ * EMB;

    f16* X16   = (f16*)d_ws;
    f16* W16   = X16  + (size_t)4096 * 1024;
    f16* Wo16  = W16  + (size_t)3072 * 1024;
    f16* Q16   = Wo16 + (size_t)1024 * 1024;
    f16* K16   = Q16  + (size_t)2 * NH * SEQ * HD;
    f16* Vt16  = K16  + (size_t)2 * NH * SEQ * HD;
    f16* ctx16 = Vt16 + (size_t)2 * NH * SEQ * HD;

    cvt_f32_f16<<<4096, 256, 0, stream>>>(query, X16, 4194304);
    cvt_f32_f16<<<1024, 256, 0, stream>>>(Wq, W16,            1048576);
    cvt_f32_f16<<<1024, 256, 0, stream>>>(Wk, W16 + 1048576,  1048576);
    cvt_f32_f16<<<1024, 256, 0, stream>>>(Wv, W16 + 2097152,  1048576);
    cvt_f32_f16<<<1024, 256, 0, stream>>>(Wo, Wo16,           1048576);

    gemm16<0><<<dim3(32, 24), 256, 0, stream>>>(X16, W16, bq, bk, bv, Q16, K16, Vt16, nullptr);
    attn16<<<256, 1024, 0, stream>>>(Q16, K16, Vt16, ctx16, meanw);
    gemm16<1><<<dim3(32, 8), 256, 0, stream>>>(ctx16, Wo16, bo, nullptr, nullptr,
                                               nullptr, nullptr, nullptr, out);
}